// Round 11
// baseline (188.835 us; speedup 1.0000x reference)
//
#include <hip/hip_runtime.h>
#include <hip/hip_fp16.h>

// Fused Conv3d(3->16, 3x3x3, VALID) + bias + channel softmax + maxpool(4,4,4)/4.
// x: [512,3,16,32,32] f32, w: [16,3,3,3,3] f32, b: [16] f32 -> out [512,16,3,7,7] f32
//
// R21: R18 (74.0 us) is jointly VALU(73%)+LDS(~70%) saturated. R18's 12.4M
// LDS bank conflicts are structural: row parity = parity(kh+dh) gives a 3/1
// bank-half imbalance on 5 of 7 K-windows (3 groups x 16 lanes on one 16-bank
// half). Fix: odd row strides (7 rows/ld, 43 rows/cin) make row parity =
// parity(cin+kd+kh) [14 even / 13 odd taps], and a tap->slot PERMUTATION in
// wtrans gives every window exactly 2 even + 2 odd rows (pad slot = zero-weight
// odd tap). With copy1 at +2088 ints (==8 mod 32), each gather phase tiles all
// 32 banks at exactly 2 lanes/bank -- the free minimum (m136).
// Permutation lives in wtrans (weights + tvi table in ws); conv loads tvi like
// it already loads wa. Everything else identical to R18: K=16 MFMA, 2 shift-
// copies, ds_read2_b32 gather, fence-pinned double buffer, batched softmax
// reduction, log2e-folded weights (raw exp2), DPP quad-max pool, inline
// epilogue index math. Controls: conflicts must DROP (else revert layout);
// WRITE_SIZE ~16.6 MB, VGPR ~48 (spill).

typedef _Float16 half4 __attribute__((ext_vector_type(4)));
typedef float f32x4 __attribute__((ext_vector_type(4)));
union H4 { int2 i; half4 h; };

template <int CTRL>
__device__ __forceinline__ float dpp_max(float x) {
  int xi = __builtin_bit_cast(int, x);
  int yi = __builtin_amdgcn_update_dpp(xi, xi, CTRL, 0xf, 0xf, false);
  return fmaxf(x, __builtin_bit_cast(float, yi));
}
// quad_perm ctrls: xor1 = [1,0,3,2] = 0xB1, xor2 = [2,3,0,1] = 0x4E

// Find the tap (0..26) for slot (v,g): parity class p = g>>1 over
// parity(cin+kd+kh), rank 2v+(g&1) within the class. Returns -1 for the one
// pad slot (p=1, rank=13).
__device__ __forceinline__ int slot_tap(int v, int g) {
  int p = g >> 1, rank = 2 * v + (g & 1);
  int tap = -1, cnt = 0;
  for (int G = 0; G < 27; ++G) {
    int cin = G / 9, kd = (G / 3) % 3, kh = G % 3;
    if (((cin + kd + kh) & 1) == p) {
      if (cnt == rank) tap = G;
      ++cnt;
    }
  }
  return tap;
}

// ws layout (ints): [0,896) wa frags (448 int2, slot-permuted, log2e-scaled);
// [896,1408) tvi per lane, 8-int stride (7 used).
__global__ void wtrans(const float* __restrict__ w, int* __restrict__ ws) {
  int t = threadIdx.x;            // 448 threads
  if (t < 448) {
    int v = t >> 6, l = t & 63;
    int c = l & 15, g = l >> 4;
    int tap = slot_tap(v, g);
    unsigned hh[4];
    for (int j = 0; j < 4; ++j) {
      float val = (tap >= 0 && j < 3)
                      ? w[c * 81 + tap * 3 + j] * 1.44269504088896f
                      : 0.0f;
      hh[j] = (unsigned)__half_as_ushort(__float2half(val));
    }
    ws[2 * t]     = (int)(hh[0] | (hh[1] << 16));
    ws[2 * t + 1] = (int)(hh[2] | (hh[3] << 16));
  }
  if (t < 64) {
    int g = t >> 4;
    for (int v = 0; v < 7; ++v) {
      int tap = slot_tap(v, g);
      if (tap < 0) tap = 9;       // pad: (cin,kd,kh)=(1,0,0), odd parity, valid row
      int cin = tap / 9, kd = (tap / 3) % 3, kh = tap % 3;
      ws[896 + t * 8 + v] = (43 * cin + 7 * kd + kh) * 16;   // T in ints
    }
    ws[896 + t * 8 + 7] = 0;
  }
}

__global__ __launch_bounds__(256, 5) void conv_sm_pool(
    const float* __restrict__ x, const int* __restrict__ ws,
    const float* __restrict__ b, float* __restrict__ out) {
  // Layout: row (cin,ld,lh) at rowIdx = 43*cin + 7*ld + lh (odd strides ->
  // row parity = parity(cin+kd+kh) ^ parity(dd+dh)); 16 ints/row, copy0 at
  // [0,2064), copy1 (shift-1-half stream) at [2088,4152) (2088 == 8 mod 32).
  // Gather: half-window Q..Q+3 -> copy Q&1, int index Q>>1 via ds_read2_b32.
  // After the main loop, [0,896) reused as pool buffer [dd*4+dh][pw][c].
  __shared__ int lds[4152];

  const int tid = threadIdx.x;
  const int blk = blockIdx.x;
  const int n = blk / 21, rr = blk % 21, pd = rr / 7, ph = rr % 7;

  const int lane = tid & 63;
  const int dd = tid >> 6;            // wave = one dd slice (0..3)
  const int l15 = lane & 15, g = lane >> 4;

  // ---- setup hoisted above staging: ws loads + index math ----
  H4 wa[7];
#pragma unroll
  for (int v = 0; v < 7; ++v)
    wa[v].i = reinterpret_cast<const int2*>(ws)[v * 64 + lane];

  int4 tv0 = *reinterpret_cast<const int4*>(&ws[896 + lane * 8]);
  int4 tv1 = *reinterpret_cast<const int4*>(&ws[896 + lane * 8 + 4]);
  int tvi[7] = {tv0.x, tv0.y, tv0.z, tv0.w, tv1.x, tv1.y, tv1.z};

  float4 b4 = *reinterpret_cast<const float4*>(b + 4 * g);

  // position bases: P = dd*224 + dh*32 + wp (halves; 7 rows per dd);
  // pbi = (P>>1) + (P&1)*2088
  int pbi[7];
#pragma unroll
  for (int tl = 0; tl < 7; ++tl) {
    int rem = tl * 16;
    int dh0 = rem / 28, rem28 = rem % 28;
    int bump = (rem28 + l15) >= 28 ? 1 : 0;
    int P = dd * 224 + (dh0 + bump) * 32 + (rem28 + l15 - 28 * bump);
    pbi[tl] = (P >> 1) + (P & 1) * 2088;
  }

  // ---- stage both copies, loop-free: 216 threads, one (row,seg) each ----
  const float* xb = x + ((size_t)n * 3 * 16 * 32 * 32)
                  + (size_t)(4 * pd) * 1024 + (size_t)(4 * ph) * 32;
  if (tid < 216) {
    int row = tid >> 1, seg = tid & 1;      // iteration row = cin*36 + ld*6 + lh
    int lh = row % 6, t2 = row / 6, ld = t2 % 6, cin = t2 / 6;
    const float* src = &xb[((cin * 16 + ld) * 32 + lh) * 32 + seg * 16];
    float4 f0 = *reinterpret_cast<const float4*>(src);
    float4 f1 = *reinterpret_cast<const float4*>(src + 4);
    float4 f2 = *reinterpret_cast<const float4*>(src + 8);
    float4 f3 = *reinterpret_cast<const float4*>(src + 12);
    float ex = src[16];
    int c[8];
    __half2 h;
    h = __float22half2_rn(make_float2(f0.x, f0.y)); c[0] = *reinterpret_cast<int*>(&h);
    h = __float22half2_rn(make_float2(f0.z, f0.w)); c[1] = *reinterpret_cast<int*>(&h);
    h = __float22half2_rn(make_float2(f1.x, f1.y)); c[2] = *reinterpret_cast<int*>(&h);
    h = __float22half2_rn(make_float2(f1.z, f1.w)); c[3] = *reinterpret_cast<int*>(&h);
    h = __float22half2_rn(make_float2(f2.x, f2.y)); c[4] = *reinterpret_cast<int*>(&h);
    h = __float22half2_rn(make_float2(f2.z, f2.w)); c[5] = *reinterpret_cast<int*>(&h);
    h = __float22half2_rn(make_float2(f3.x, f3.y)); c[6] = *reinterpret_cast<int*>(&h);
    h = __float22half2_rn(make_float2(f3.z, f3.w)); c[7] = *reinterpret_cast<int*>(&h);
    int eh = (int)__half_as_ushort(__float2half(ex));
    int s[8];
#pragma unroll
    for (int k = 0; k < 7; ++k) s[k] = __builtin_amdgcn_alignbit(c[k + 1], c[k], 16);
    s[7] = __builtin_amdgcn_alignbit(eh, c[7], 16);
    int li = (43 * cin + 7 * ld + lh) * 16 + seg * 8;
    int4 w0; w0.x = c[0]; w0.y = c[1]; w0.z = c[2]; w0.w = c[3];
    int4 w1; w1.x = c[4]; w1.y = c[5]; w1.z = c[6]; w1.w = c[7];
    *reinterpret_cast<int4*>(&lds[li])     = w0;
    *reinterpret_cast<int4*>(&lds[li + 4]) = w1;
    int4 w2; w2.x = s[0]; w2.y = s[1]; w2.z = s[2]; w2.w = s[3];
    int4 w3; w3.x = s[4]; w3.y = s[5]; w3.z = s[6]; w3.w = s[7];
    *reinterpret_cast<int4*>(&lds[2088 + li])     = w2;
    *reinterpret_cast<int4*>(&lds[2088 + li + 4]) = w3;
  }
  __syncthreads();

  // acc init with bias (row = channel = 4g+q), log2e pre-scaled
  f32x4 acc[7];
  f32x4 binit;
  binit[0] = b4.x * 1.44269504088896f;
  binit[1] = b4.y * 1.44269504088896f;
  binit[2] = b4.z * 1.44269504088896f;
  binit[3] = b4.w * 1.44269504088896f;
#pragma unroll
  for (int tl = 0; tl < 7; ++tl) acc[tl] = binit;

  // ---- main: 7 K-windows x 7 N-tiles, double-buffered, fence-pinned ----
  H4 bfA[7], bfB[7];
#pragma unroll
  for (int tl = 0; tl < 7; ++tl) {
    const int* p = &lds[pbi[tl] + tvi[0]];
    bfA[tl].i.x = p[0]; bfA[tl].i.y = p[1];
  }
  __builtin_amdgcn_sched_barrier(0);
#pragma unroll
  for (int vv = 0; vv < 3; ++vv) {
    const int v0 = 2 * vv, v1 = 2 * vv + 1, v2 = 2 * vv + 2;
#pragma unroll
    for (int tl = 0; tl < 7; ++tl) {
      const int* p = &lds[pbi[tl] + tvi[v1]];
      bfB[tl].i.x = p[0]; bfB[tl].i.y = p[1];
    }
    __builtin_amdgcn_sched_barrier(0);
#pragma unroll
    for (int tl = 0; tl < 7; ++tl)
      acc[tl] = __builtin_amdgcn_mfma_f32_16x16x16f16(wa[v0].h, bfA[tl].h, acc[tl], 0, 0, 0);
    __builtin_amdgcn_sched_barrier(0);
#pragma unroll
    for (int tl = 0; tl < 7; ++tl) {
      const int* p = &lds[pbi[tl] + tvi[v2]];
      bfA[tl].i.x = p[0]; bfA[tl].i.y = p[1];
    }
    __builtin_amdgcn_sched_barrier(0);
#pragma unroll
    for (int tl = 0; tl < 7; ++tl)
      acc[tl] = __builtin_amdgcn_mfma_f32_16x16x16f16(wa[v1].h, bfB[tl].h, acc[tl], 0, 0, 0);
    __builtin_amdgcn_sched_barrier(0);
  }
#pragma unroll
  for (int tl = 0; tl < 7; ++tl)
    acc[tl] = __builtin_amdgcn_mfma_f32_16x16x16f16(wa[6].h, bfA[tl].h, acc[tl], 0, 0, 0);

  // ---- epilogue: softmax over channels (batched reductions), pool ----
  __syncthreads();      // all LDS tile reads done; reuse lds as pool buffer
  float* pool2 = reinterpret_cast<float*>(lds);   // [dd*4+dh][pw][c]

  // phase 1: exp2 in place (acc regs reused), per-tile channel-group sums
  float s4[7];
#pragma unroll
  for (int tl = 0; tl < 7; ++tl) {
#pragma unroll
    for (int q = 0; q < 4; ++q) acc[tl][q] = __builtin_amdgcn_exp2f(acc[tl][q]);
    s4[tl] = (acc[tl][0] + acc[tl][1]) + (acc[tl][2] + acc[tl][3]);
  }
  // phase 2: batched cross-group butterflies (7 independent chains pipeline)
  float t7[7];
#pragma unroll
  for (int tl = 0; tl < 7; ++tl) t7[tl] = __shfl_xor(s4[tl], 16, 64);
#pragma unroll
  for (int tl = 0; tl < 7; ++tl) s4[tl] += t7[tl];
#pragma unroll
  for (int tl = 0; tl < 7; ++tl) t7[tl] = __shfl_xor(s4[tl], 32, 64);
#pragma unroll
  for (int tl = 0; tl < 7; ++tl) s4[tl] += t7[tl];
#pragma unroll
  for (int tl = 0; tl < 7; ++tl) s4[tl] = __builtin_amdgcn_rcpf(s4[tl]);

  // phase 3: normalize, DPP quad-max, pool write
#pragma unroll
  for (int tl = 0; tl < 7; ++tl) {
    float pm[4];
#pragma unroll
    for (int q = 0; q < 4; ++q) pm[q] = acc[tl][q] * s4[tl];
#pragma unroll
    for (int q = 0; q < 4; ++q) {
      pm[q] = dpp_max<0xB1>(pm[q]);   // wp xor1
      pm[q] = dpp_max<0x4E>(pm[q]);   // wp xor2
    }
    if ((l15 & 3) == 0) {
      int rem = tl * 16;
      int dh0 = rem / 28, rem28 = rem % 28;
      int bump = (rem28 + l15) >= 28 ? 1 : 0;
      int dh = dh0 + bump;
      int pw = (rem28 + l15 - 28 * bump) >> 2;
      float4 val = {pm[0], pm[1], pm[2], pm[3]};
      *reinterpret_cast<float4*>(&pool2[(((dd * 4 + dh) * 7 + pw) << 4) + 4 * g]) = val;
    }
  }
  __syncthreads();

  // tail: pair (tid, tid^1) split the 16 slots 8/8, DPP pair-max
  if (tid < 224) {
    int idx = tid >> 1, h = tid & 1;
    int c = idx / 7, pw = idx % 7;
    float m = pool2[(((h * 8) * 7 + pw) << 4) + c];
#pragma unroll
    for (int s2 = 1; s2 < 8; ++s2)
      m = fmaxf(m, pool2[(((h * 8 + s2) * 7 + pw) << 4) + c]);
    m = dpp_max<0xB1>(m);   // combine with partner (lanes 2k,2k+1)
    if (h == 0)
      out[(((size_t)n * 16 + c) * 3 + pd) * 49 + (size_t)ph * 7 + pw] = m;
  }
}

extern "C" void kernel_launch(void* const* d_in, const int* in_sizes, int n_in,
                              void* d_out, int out_size, void* d_ws, size_t ws_size,
                              hipStream_t stream) {
  const float* x = (const float*)d_in[0];
  const float* w = (const float*)d_in[1];
  const float* b = (const float*)d_in[2];
  float* out = (float*)d_out;
  int* ws = (int*)d_ws;    // 1408 ints: wa frags + tvi table
  (void)in_sizes; (void)n_in; (void)out_size; (void)ws_size;
  hipLaunchKernelGGL(wtrans, dim3(1), dim3(448), 0, stream, w, ws);
  hipLaunchKernelGGL(conv_sm_pool, dim3(512 * 3 * 7), dim3(256), 0, stream,
                     x, ws, b, out);
}